// Round 6
// baseline (472.988 us; speedup 1.0000x reference)
//
#include <hip/hip_runtime.h>
#include <cmath>

#define D_MODEL 1792
#define BB      256
#define II      2048          // inner dim
#define FOURI   8192

__device__ __forceinline__ float sigm(float v) { return 1.0f / (1.0f + expf(-v)); }

__device__ __forceinline__ float waveReduce(float s) {
    #pragma unroll
    for (int off = 32; off > 0; off >>= 1) s += __shfl_down(s, off, 64);
    return s;
}

// Agent-coherent scalar accessors: RELAXED atomics bypass stale caches to the
// coherence point WITHOUT buffer_inv/buffer_wbl2 (acquire/release fences
// destroyed streaming BW in R4). Proven correct in R5 (absmax 0.0).
__device__ __forceinline__ float ldc(const float* p) {
    return __hip_atomic_load(p, __ATOMIC_RELAXED, __HIP_MEMORY_SCOPE_AGENT);
}
__device__ __forceinline__ void stc(float* p, float v) {
    __hip_atomic_store(p, v, __ATOMIC_RELAXED, __HIP_MEMORY_SCOPE_AGENT);
}

// dot of one 2048-wide weight row with concat(x_t[1792], y_t[256]) (cached)
__device__ __forceinline__ float dotConcat(const float* __restrict__ wrow,
                                           const float* __restrict__ xt,
                                           const float* __restrict__ yt,
                                           int lane) {
    float sum = 0.f;
    #pragma unroll
    for (int p = 0; p < 8; ++p) {
        const int j = p * 256 + lane * 4;
        float4 w = *(const float4*)(wrow + j);
        float4 v = (p < 7) ? *(const float4*)(xt + j)
                           : *(const float4*)(yt + (j - D_MODEL));
        sum += w.x * v.x + w.y * v.y + w.z * v.z + w.w * v.w;
    }
    return sum;
}

// dot of one 2048-wide weight row (cached) with h staged in LDS
__device__ __forceinline__ float dotLds(const float* __restrict__ wrow,
                                        const float* hs, int lane) {
    float sum = 0.f;
    #pragma unroll
    for (int p = 0; p < 8; ++p) {
        const int j = p * 256 + lane * 4;
        float4 w = *(const float4*)(wrow + j);
        float4 v = *(const float4*)(hs + j);   // ds_read_b128, 2-way = free
        sum += w.x * v.x + w.y * v.y + w.z * v.z + w.w * v.w;
    }
    return sum;
}

__global__ __launch_bounds__(256, 8) void lstm_pipe(
    const float* __restrict__ x,     // (6,1792)
    const float* __restrict__ y,     // (5,256)
    const float* __restrict__ Wih5,  // (5,8192,2048)
    const float* __restrict__ Whh5,  // (5,8192,2048)
    const float* __restrict__ bih5,  // (5,8192)
    const float* __restrict__ bhh5,  // (5,8192)
    const float* __restrict__ WihF,  // (8192,1792)
    const float* __restrict__ WhhF,  // (8192,2048)
    const float* __restrict__ bihF,  // (8192)
    const float* __restrict__ bhhF,  // (8192)
    float* __restrict__ out,         // (256)
    float* __restrict__ gihAll,      // (4,8192) gih for steps 1..4
    float* __restrict__ gihF,        // (1024) compact [gate][256]
    float* __restrict__ hbuf,        // (5,2048)
    float* __restrict__ cbuf,        // (2048)
    int* __restrict__ ctl,           // [0] = barrier counter (pre-zeroed)
    int G)
{
    const int b    = blockIdx.x;
    const int tid  = threadIdx.x;
    const int wave = tid >> 6;       // = gate index for cell work
    const int lane = tid & 63;
    const int W    = b * 4 + wave;   // global wave id, [0, 4G)
    __shared__ float hs[II];
    __shared__ float partial[4];

    // Grid barrier, cache-maintenance-free (RELAXED only; __syncthreads'
    // vmcnt drain makes all waves' sc-stores globally visible first).
    auto gridbar = [&](int target) {
        __syncthreads();
        if (tid == 0) {
            asm volatile("s_waitcnt vmcnt(0)" ::: "memory");
            __hip_atomic_fetch_add(ctl, 1, __ATOMIC_RELAXED,
                                   __HIP_MEMORY_SCOPE_AGENT);
            while (__hip_atomic_load(ctl, __ATOMIC_RELAXED,
                                     __HIP_MEMORY_SCOPE_AGENT) < target)
                __builtin_amdgcn_s_sleep(8);
        }
        __syncthreads();
    };

    auto stage_h = [&](const float* hsrc) {
        for (int i = tid; i < II; i += 256) hs[i] = ldc(hsrc + i);
        __syncthreads();
    };

    // ---- one ih row (raw row 0..8191) for step tt in 1..4 ----
    auto ih_row = [&](int tt, int row) {
        const float* wrow = Wih5 + ((size_t)tt * FOURI + row) * (size_t)II;
        float s = dotConcat(wrow, x + tt * D_MODEL, y + tt * BB, lane);
        s = waveReduce(s);
        if (lane == 0)
            stc(gihAll + (size_t)(tt - 1) * FOURI + row,
                s + bih5[tt * FOURI + row] + bhh5[tt * FOURI + row]);
    };

    // ---- one final-cell ih row, j in [0,1024): gate=j>>8, col=j&255 ----
    auto ihF_row = [&](int j) {
        const int row = (j >> 8) * II + D_MODEL + (j & 255);
        const float* wrow = WihF + (size_t)row * (size_t)D_MODEL;
        const float* x5 = x + 5 * D_MODEL;
        float s = 0.f;
        #pragma unroll
        for (int p = 0; p < 7; ++p) {
            const int jj = p * 256 + lane * 4;
            float4 w = *(const float4*)(wrow + jj);
            float4 v = *(const float4*)(x5 + jj);
            s += w.x * v.x + w.y * v.y + w.z * v.z + w.w * v.w;
        }
        s = waveReduce(s);
        if (lane == 0) stc(gihF + j, s + bihF[row] + bhhF[row]);
    };

    // ========== 5 phases: every wave = 1 cell gate-dot + 1 filler row =====
    for (int t = 0; t < 5; ++t) {
        if (t > 0) stage_h(hbuf + (size_t)(t - 1) * II);

        // --- cell: block b owns row r; wave q computes gate q ---
        for (int r = b; r < II; r += G) {
            float s = 0.f;
            bool active = true;
            if (t == 0) {
                if (wave == 1) active = false;          // f-gate unused (c0=0)
                else {
                    const float* wrow =
                        Wih5 + ((size_t)wave * II + r) * (size_t)II;
                    s = dotConcat(wrow, x, y, lane);
                }
            } else {
                const float* wrow = Whh5 + (size_t)t * FOURI * II +
                                    ((size_t)wave * II + r) * (size_t)II;
                s = dotLds(wrow, hs, lane);
            }
            if (active) {
                s = waveReduce(s);
                if (lane == 0) {
                    if (t == 0)
                        partial[wave] = s + bih5[wave * II + r]
                                          + bhh5[wave * II + r];
                    else
                        partial[wave] = s +
                            ldc(gihAll + (size_t)(t - 1) * FOURI
                                + wave * II + r);
                }
            }
            __syncthreads();
            if (tid == 0) {
                float cc;
                if (t == 0) cc = sigm(partial[0]) * tanhf(partial[2]);
                else        cc = sigm(partial[1]) * ldc(cbuf + r)
                               + sigm(partial[0]) * tanhf(partial[2]);
                stc(cbuf + r, cc);
                stc(hbuf + (size_t)t * II + r, sigm(partial[3]) * tanhf(cc));
            }
            __syncthreads();
        }

        // --- filler: phases 0-3 stream ih for step t+1 (1 row per wave);
        //     phase 4 streams the final-cell ih rows (first 1024 waves) ---
        if (t < 4) {
            for (int i = W; i < FOURI; i += 4 * G) ih_row(t + 1, i);
        } else {
            for (int j = W; j < 1024; j += 4 * G) ihF_row(j);
        }

        gridbar((t + 1) * G);
    }

    // ========== final cell: rows 1792..2047 -> out[0..255] ==========
    if (b < BB || G < BB) {
        stage_h(hbuf + 4 * (size_t)II);
        for (int k = b; k < BB; k += G) {
            const int r = D_MODEL + k;
            const float* wrow = WhhF + ((size_t)wave * II + r) * (size_t)II;
            float s = dotLds(wrow, hs, lane);
            s = waveReduce(s);
            if (lane == 0) partial[wave] = s + ldc(gihF + wave * BB + k);
            __syncthreads();
            if (tid == 0) {
                const float cc = sigm(partial[1]) * ldc(cbuf + r)
                               + sigm(partial[0]) * tanhf(partial[2]);
                out[k] = sigm(partial[3]) * tanhf(cc);
            }
            __syncthreads();
        }
    }
}

extern "C" void kernel_launch(void* const* d_in, const int* in_sizes, int n_in,
                              void* d_out, int out_size, void* d_ws, size_t ws_size,
                              hipStream_t stream) {
    const float* x    = (const float*)d_in[0];
    const float* y    = (const float*)d_in[1];
    const float* Wih5 = (const float*)d_in[2];
    const float* Whh5 = (const float*)d_in[3];
    const float* bih5 = (const float*)d_in[4];
    const float* bhh5 = (const float*)d_in[5];
    const float* WihF = (const float*)d_in[6];
    const float* WhhF = (const float*)d_in[7];
    const float* bihF = (const float*)d_in[8];
    const float* bhhF = (const float*)d_in[9];
    float* out = (float*)d_out;

    int*   ctl    = (int*)d_ws;
    float* fbase  = (float*)((char*)d_ws + 256);
    float* gihAll = fbase;                     // 4*8192
    float* gihF   = gihAll + 4 * FOURI;        // 1024
    float* hbuf   = gihF + 1024;               // 5*2048
    float* cbuf   = hbuf + 5 * II;             // 2048

    // Co-residency by construction (capture-safe host-side queries only).
    // Target 8 blocks/CU (32 waves/CU) — throughput scales with resident waves.
    int G = 2048;
    int maxB = 0;
    if (hipOccupancyMaxActiveBlocksPerMultiprocessor(&maxB, lstm_pipe, 256, 0)
            == hipSuccess && maxB >= 1) {
        int numCU = 256;
        hipDevice_t dev;
        int cu = 0;
        if (hipGetDevice(&dev) == hipSuccess &&
            hipDeviceGetAttribute(&cu, hipDeviceAttributeMultiprocessorCount,
                                  dev) == hipSuccess && cu > 0)
            numCU = cu;
        long cap = (long)maxB * numCU;
        if (cap < G) G = (int)cap;
        if (G < 1) G = 1;
    }

    hipMemsetAsync(ctl, 0, 64, stream);   // zero barrier counter (in-graph)

    lstm_pipe<<<G, 256, 0, stream>>>(x, y, Wih5, Whh5, bih5, bhh5,
                                     WihF, WhhF, bihF, bhhF, out,
                                     gihAll, gihF, hbuf, cbuf, ctl, G);
}

// Round 7
// 122.320 us; speedup vs baseline: 3.8668x; 3.8668x over previous
//
#include <hip/hip_runtime.h>
#include <cmath>

#define D_MODEL 1792
#define BB      256
#define II      2048          // inner dim
#define FOURI   8192

__device__ __forceinline__ float sigm(float v) { return 1.0f / (1.0f + expf(-v)); }

__device__ __forceinline__ float waveReduce(float s) {
    #pragma unroll
    for (int off = 32; off > 0; off >>= 1) s += __shfl_down(s, off, 64);
    return s;
}

// stage a contiguous 2048-float vector into LDS (512 float4, 2 iters/thread)
__device__ __forceinline__ void stage2048(float* dst, const float* src, int tid) {
    float4* d4 = (float4*)dst;
    const float4* s4 = (const float4*)src;
    d4[tid]       = s4[tid];
    d4[tid + 256] = s4[tid + 256];
    __syncthreads();
}

// stage concat(x_t[1792], y_t[256]) into LDS
__device__ __forceinline__ void stageConcat(float* dst, const float* xt,
                                            const float* yt, int tid) {
    float4* d4 = (float4*)dst;
    const float4* x4 = (const float4*)xt;
    const float4* y4 = (const float4*)yt;
    int i = tid;
    d4[i] = (i < 448) ? x4[i] : y4[i - 448];
    i = tid + 256;
    d4[i] = (i < 448) ? x4[i] : y4[i - 448];
    __syncthreads();
}

// dot of one 2048-wide weight row (global, streamed) with LDS vector
__device__ __forceinline__ float dotLds(const float* __restrict__ w,
                                        const float* hs, int lane) {
    float s = 0.f;
    #pragma unroll
    for (int p = 0; p < 8; ++p) {
        const int j = p * 256 + lane * 4;
        float4 a = *(const float4*)(w + j);
        float4 b = *(const float4*)(hs + j);
        s += a.x * b.x + a.y * b.y + a.z * b.z + a.w * b.w;
    }
    return s;
}

// ---------------------------------------------------------------------------
// K0: blocks 0..2047: step-0 cell row b — waves 0,2,3 do gates i,g,o (f-gate
//     skipped: c0=0); wave 1 does step-1 ih row b (global inpt1, L2-hot).
//     blocks 2048..3583: step-1 ih rows 2048..8191 (4 waves x 1 row, LDS inpt1).
// ---------------------------------------------------------------------------
__global__ __launch_bounds__(256) void k0(
    const float* __restrict__ x, const float* __restrict__ y,
    const float* __restrict__ Wih5,
    const float* __restrict__ bih5, const float* __restrict__ bhh5,
    float* __restrict__ h0, float* __restrict__ c0, float* __restrict__ gih1)
{
    __shared__ float buf[II];
    __shared__ float partial[4];
    const int tid = threadIdx.x, wave = tid >> 6, lane = tid & 63;
    const int b = blockIdx.x;

    if (b < II) {
        stageConcat(buf, x, y, tid);
        if (wave != 1) {
            const float* wr = Wih5 + ((size_t)wave * II + b) * (size_t)II;
            float s = dotLds(wr, buf, lane);
            s = waveReduce(s);
            if (lane == 0)
                partial[wave] = s + bih5[wave * II + b] + bhh5[wave * II + b];
        } else {
            // filler: step-1 ih row b (gate-i rows), inpt1 from global (L2)
            const float* wr = Wih5 + ((size_t)FOURI + b) * (size_t)II;
            const float* xt = x + D_MODEL;
            const float* yt = y + BB;
            float s = 0.f;
            #pragma unroll
            for (int p = 0; p < 8; ++p) {
                const int j = p * 256 + lane * 4;
                float4 a = *(const float4*)(wr + j);
                float4 v = (p < 7) ? *(const float4*)(xt + j)
                                   : *(const float4*)(yt + (j - D_MODEL));
                s += a.x * v.x + a.y * v.y + a.z * v.z + a.w * v.w;
            }
            s = waveReduce(s);
            if (lane == 0)
                gih1[b] = s + bih5[FOURI + b] + bhh5[FOURI + b];
        }
        __syncthreads();
        if (tid == 0) {
            const float cc = sigm(partial[0]) * tanhf(partial[2]);
            c0[b] = cc;
            h0[b] = sigm(partial[3]) * tanhf(cc);
        }
    } else {
        stageConcat(buf, x + D_MODEL, y + BB, tid);
        const int row = II + (b - II) * 4 + wave;   // 2048..8191
        const float* wr = Wih5 + ((size_t)FOURI + row) * (size_t)II;
        float s = dotLds(wr, buf, lane);
        s = waveReduce(s);
        if (lane == 0)
            gih1[row] = s + bih5[FOURI + row] + bhh5[FOURI + row];
    }
}

// ---------------------------------------------------------------------------
// K1..K3: blocks 0..2047: recurrent cell row b for step t (h staged in LDS);
//         blocks 2048..4095: ih rows for step t+1 (inpt staged in LDS).
// ---------------------------------------------------------------------------
__global__ __launch_bounds__(256) void kmid(
    const float* __restrict__ Whh,    // (8192,2048) step t
    const float* __restrict__ gih_t,  // (8192)
    const float* __restrict__ h_in, float* __restrict__ h_out,
    float* __restrict__ c,
    const float* __restrict__ WihN,   // (8192,2048) step t+1
    const float* __restrict__ bihN, const float* __restrict__ bhhN,
    const float* __restrict__ xN, const float* __restrict__ yN,
    float* __restrict__ gihN)
{
    __shared__ float buf[II];
    __shared__ float partial[4];
    const int tid = threadIdx.x, wave = tid >> 6, lane = tid & 63;
    const int b = blockIdx.x;

    if (b < II) {
        stage2048(buf, h_in, tid);
        const float* wr = Whh + ((size_t)wave * II + b) * (size_t)II;
        float s = dotLds(wr, buf, lane);
        s = waveReduce(s);
        if (lane == 0) partial[wave] = s + gih_t[wave * II + b];
        __syncthreads();
        if (tid == 0) {
            const float cc = sigm(partial[1]) * c[b]
                           + sigm(partial[0]) * tanhf(partial[2]);
            c[b] = cc;
            h_out[b] = sigm(partial[3]) * tanhf(cc);
        }
    } else {
        stageConcat(buf, xN, yN, tid);
        const int row = (b - II) * 4 + wave;       // 0..8191
        const float* wr = WihN + (size_t)row * (size_t)II;
        float s = dotLds(wr, buf, lane);
        s = waveReduce(s);
        if (lane == 0) gihN[row] = s + bihN[row] + bhhN[row];
    }
}

// ---------------------------------------------------------------------------
// K4: blocks 0..2047: cell step 4; blocks 2048..2303: final-cell ih rows
//     (1024 rows over x5, 7 KB each, compact store).
// ---------------------------------------------------------------------------
__global__ __launch_bounds__(256) void k4(
    const float* __restrict__ Whh4, const float* __restrict__ gih4,
    const float* __restrict__ h_in, float* __restrict__ h_out,
    float* __restrict__ c,
    const float* __restrict__ WihF, const float* __restrict__ bihF,
    const float* __restrict__ bhhF, const float* __restrict__ x5,
    float* __restrict__ gihF)
{
    __shared__ float buf[II];
    __shared__ float partial[4];
    const int tid = threadIdx.x, wave = tid >> 6, lane = tid & 63;
    const int b = blockIdx.x;

    if (b < II) {
        stage2048(buf, h_in, tid);
        const float* wr = Whh4 + ((size_t)wave * II + b) * (size_t)II;
        float s = dotLds(wr, buf, lane);
        s = waveReduce(s);
        if (lane == 0) partial[wave] = s + gih4[wave * II + b];
        __syncthreads();
        if (tid == 0) {
            const float cc = sigm(partial[1]) * c[b]
                           + sigm(partial[0]) * tanhf(partial[2]);
            c[b] = cc;
            h_out[b] = sigm(partial[3]) * tanhf(cc);
        }
    } else {
        // stage x5 (1792 floats = 448 float4)
        float4* d4 = (float4*)buf;
        const float4* s4 = (const float4*)x5;
        d4[tid] = (tid < 448) ? s4[tid] : make_float4(0.f, 0.f, 0.f, 0.f);
        if (tid < 192) d4[tid + 256] = s4[tid + 256];
        __syncthreads();
        const int j = (b - II) * 4 + wave;          // 0..1023
        const int row = (j >> 8) * II + D_MODEL + (j & 255);
        const float* wr = WihF + (size_t)row * (size_t)D_MODEL;
        float s = 0.f;
        #pragma unroll
        for (int p = 0; p < 7; ++p) {
            const int jj = p * 256 + lane * 4;
            float4 a = *(const float4*)(wr + jj);
            float4 v = *(const float4*)(buf + jj);
            s += a.x * v.x + a.y * v.y + a.z * v.z + a.w * v.w;
        }
        s = waveReduce(s);
        if (lane == 0) gihF[j] = s + bihF[row] + bhhF[row];
    }
}

// ---------------------------------------------------------------------------
// K5: final cell, rows 1792..2047 -> out[0..255].
// ---------------------------------------------------------------------------
__global__ __launch_bounds__(256) void k5(
    const float* __restrict__ WhhF, const float* __restrict__ gihF,
    const float* __restrict__ h_in, const float* __restrict__ c,
    float* __restrict__ out)
{
    __shared__ float buf[II];
    __shared__ float partial[4];
    const int tid = threadIdx.x, wave = tid >> 6, lane = tid & 63;
    const int b = blockIdx.x;                     // 0..255

    stage2048(buf, h_in, tid);
    const int r = D_MODEL + b;
    const float* wr = WhhF + ((size_t)wave * II + r) * (size_t)II;
    float s = dotLds(wr, buf, lane);
    s = waveReduce(s);
    if (lane == 0) partial[wave] = s + gihF[wave * BB + b];
    __syncthreads();
    if (tid == 0) {
        const float cc = sigm(partial[1]) * c[r]
                       + sigm(partial[0]) * tanhf(partial[2]);
        out[b] = sigm(partial[3]) * tanhf(cc);
    }
}

extern "C" void kernel_launch(void* const* d_in, const int* in_sizes, int n_in,
                              void* d_out, int out_size, void* d_ws, size_t ws_size,
                              hipStream_t stream) {
    const float* x    = (const float*)d_in[0];
    const float* y    = (const float*)d_in[1];
    const float* Wih5 = (const float*)d_in[2];
    const float* Whh5 = (const float*)d_in[3];
    const float* bih5 = (const float*)d_in[4];
    const float* bhh5 = (const float*)d_in[5];
    const float* WihF = (const float*)d_in[6];
    const float* WhhF = (const float*)d_in[7];
    const float* bihF = (const float*)d_in[8];
    const float* bhhF = (const float*)d_in[9];
    float* out = (float*)d_out;

    float* ws   = (float*)d_ws;
    float* gihA = ws;                  // 8192
    float* gihB = gihA + FOURI;        // 8192
    float* gihF = gihB + FOURI;        // 1024
    float* hA   = gihF + 1024;         // 2048
    float* hB   = hA + II;             // 2048
    float* cbuf = hB + II;             // 2048

    const size_t WOFF = (size_t)FOURI * II;

    // K0: step-0 cell (f-gate skipped) + step-1 ih -> gihA, h0 -> hA
    k0<<<3584, 256, 0, stream>>>(x, y, Wih5, bih5, bhh5, hA, cbuf, gihA);

    // K1: step 1 (gihA, hA->hB) + step-2 ih -> gihB
    kmid<<<4096, 256, 0, stream>>>(
        Whh5 + 1 * WOFF, gihA, hA, hB, cbuf,
        Wih5 + 2 * WOFF, bih5 + 2 * FOURI, bhh5 + 2 * FOURI,
        x + 2 * D_MODEL, y + 2 * BB, gihB);

    // K2: step 2 (gihB, hB->hA) + step-3 ih -> gihA
    kmid<<<4096, 256, 0, stream>>>(
        Whh5 + 2 * WOFF, gihB, hB, hA, cbuf,
        Wih5 + 3 * WOFF, bih5 + 3 * FOURI, bhh5 + 3 * FOURI,
        x + 3 * D_MODEL, y + 3 * BB, gihA);

    // K3: step 3 (gihA, hA->hB) + step-4 ih -> gihB
    kmid<<<4096, 256, 0, stream>>>(
        Whh5 + 3 * WOFF, gihA, hA, hB, cbuf,
        Wih5 + 4 * WOFF, bih5 + 4 * FOURI, bhh5 + 4 * FOURI,
        x + 4 * D_MODEL, y + 4 * BB, gihB);

    // K4: step 4 (gihB, hB->hA) + final-cell ih -> gihF
    k4<<<2304, 256, 0, stream>>>(
        Whh5 + 4 * WOFF, gihB, hB, hA, cbuf,
        WihF, bihF, bhhF, x + 5 * D_MODEL, gihF);

    // K5: final cell -> out
    k5<<<BB, 256, 0, stream>>>(WhhF, gihF, hA, cbuf, out);
}

// Round 8
// 120.101 us; speedup vs baseline: 3.9382x; 1.0185x over previous
//
#include <hip/hip_runtime.h>
#include <cmath>

#define D_MODEL 1792
#define BB      256
#define II      2048          // inner dim
#define FOURI   8192
#define G       2048          // grid: whole resident rounds (1024|2048 both divide)

__device__ __forceinline__ float sigm(float v) { return 1.0f / (1.0f + expf(-v)); }

__device__ __forceinline__ float waveReduce(float s) {
    #pragma unroll
    for (int off = 32; off > 0; off >>= 1) s += __shfl_down(s, off, 64);
    return s;
}

// dot of one 2048-wide weight row with a contiguous 2048 vector (both global)
__device__ __forceinline__ float dotG(const float* __restrict__ w,
                                      const float* __restrict__ v, int lane) {
    float s = 0.f;
    #pragma unroll
    for (int p = 0; p < 8; ++p) {
        const int j = p * 256 + lane * 4;
        float4 a = *(const float4*)(w + j);
        float4 b = *(const float4*)(v + j);
        s += a.x * b.x + a.y * b.y + a.z * b.z + a.w * b.w;
    }
    return s;
}

// dot of one 2048-wide weight row with concat(x_t[1792], y_t[256])
__device__ __forceinline__ float dotConcat(const float* __restrict__ w,
                                           const float* __restrict__ xt,
                                           const float* __restrict__ yt,
                                           int lane) {
    float s = 0.f;
    #pragma unroll
    for (int p = 0; p < 8; ++p) {
        const int j = p * 256 + lane * 4;
        float4 a = *(const float4*)(w + j);
        float4 b = (p < 7) ? *(const float4*)(xt + j)
                           : *(const float4*)(yt + (j - D_MODEL));
        s += a.x * b.x + a.y * b.y + a.z * b.z + a.w * b.w;
    }
    return s;
}

// ---------------------------------------------------------------------------
// K0: 4096 tasks on 2048 blocks (2.0/block).
//   task b        : step-0 cell row b (waves 0,2,3 = gates i,g,o; f skipped)
//   task b+2048   : ih1 quad b (rows 4b..4b+3 of Wih5[1], contiguous 32KB)
// ---------------------------------------------------------------------------
__global__ __launch_bounds__(256) void k_first(
    const float* __restrict__ x, const float* __restrict__ y,
    const float* __restrict__ Wih5,
    const float* __restrict__ bih5, const float* __restrict__ bhh5,
    float* __restrict__ h0, float* __restrict__ c0, float* __restrict__ gih1)
{
    __shared__ float partial[4];
    const int tid = threadIdx.x, wave = tid >> 6, lane = tid & 63;
    const int b = blockIdx.x;

    // --- cell0 row b ---
    if (wave != 1) {
        const float* wr = Wih5 + ((size_t)wave * II + b) * (size_t)II;
        float s = dotConcat(wr, x, y, lane);
        s = waveReduce(s);
        if (lane == 0)
            partial[wave] = s + bih5[wave * II + b] + bhh5[wave * II + b];
    }
    __syncthreads();
    if (tid == 0) {
        const float cc = sigm(partial[0]) * tanhf(partial[2]);
        c0[b] = cc;
        h0[b] = sigm(partial[3]) * tanhf(cc);
    }

    // --- ih1 quad b: row 4b+wave ---
    {
        const int row = b * 4 + wave;
        const float* wr = Wih5 + ((size_t)FOURI + row) * (size_t)II;
        float s = dotConcat(wr, x + D_MODEL, y + BB, lane);
        s = waveReduce(s);
        if (lane == 0)
            gih1[row] = s + bih5[FOURI + row] + bhh5[FOURI + row];
    }
}

// ---------------------------------------------------------------------------
// K1..K3: 4096 tasks on 2048 blocks (2.0/block).
//   task b      : cell row b for step t (4 gates over Whh, RHS h_in)
//   task b+2048 : ih quad b for step t+1
// ---------------------------------------------------------------------------
__global__ __launch_bounds__(256) void k_mid(
    const float* __restrict__ Whh,    // (8192,2048) step t
    const float* __restrict__ gih_t,  // (8192)
    const float* __restrict__ h_in, float* __restrict__ h_out,
    float* __restrict__ c,
    const float* __restrict__ WihN,   // (8192,2048) step t+1
    const float* __restrict__ bihN, const float* __restrict__ bhhN,
    const float* __restrict__ xN, const float* __restrict__ yN,
    float* __restrict__ gihN)
{
    __shared__ float partial[4];
    const int tid = threadIdx.x, wave = tid >> 6, lane = tid & 63;
    const int b = blockIdx.x;

    // --- cell row b ---
    {
        const float* wr = Whh + ((size_t)wave * II + b) * (size_t)II;
        float s = dotG(wr, h_in, lane);
        s = waveReduce(s);
        if (lane == 0) partial[wave] = s + gih_t[wave * II + b];
    }
    __syncthreads();
    if (tid == 0) {
        const float cc = sigm(partial[1]) * c[b]
                       + sigm(partial[0]) * tanhf(partial[2]);
        c[b] = cc;
        h_out[b] = sigm(partial[3]) * tanhf(cc);
    }

    // --- ih quad b for step t+1: row 4b+wave ---
    {
        const int row = b * 4 + wave;
        const float* wr = WihN + (size_t)row * (size_t)II;
        float s = dotConcat(wr, xN, yN, lane);
        s = waveReduce(s);
        if (lane == 0) gihN[row] = s + bihN[row] + bhhN[row];
    }
}

// ---------------------------------------------------------------------------
// K4: 2304 tasks on 2048 blocks.
//   task b            : cell row b for step 4
//   task b+2048 (b<256): final-cell ih quad b (compact rows 4b..4b+3)
// ---------------------------------------------------------------------------
__global__ __launch_bounds__(256) void k4(
    const float* __restrict__ Whh4, const float* __restrict__ gih4,
    const float* __restrict__ h_in, float* __restrict__ h_out,
    float* __restrict__ c,
    const float* __restrict__ WihF, const float* __restrict__ bihF,
    const float* __restrict__ bhhF, const float* __restrict__ x5,
    float* __restrict__ gihF)
{
    __shared__ float partial[4];
    const int tid = threadIdx.x, wave = tid >> 6, lane = tid & 63;
    const int b = blockIdx.x;

    // --- cell row b (step 4) ---
    {
        const float* wr = Whh4 + ((size_t)wave * II + b) * (size_t)II;
        float s = dotG(wr, h_in, lane);
        s = waveReduce(s);
        if (lane == 0) partial[wave] = s + gih4[wave * II + b];
    }
    __syncthreads();
    if (tid == 0) {
        const float cc = sigm(partial[1]) * c[b]
                       + sigm(partial[0]) * tanhf(partial[2]);
        c[b] = cc;
        h_out[b] = sigm(partial[3]) * tanhf(cc);
    }

    // --- final-cell ih quad (blocks 0..255): compact j = 4b+wave ---
    if (b < BB) {
        const int j = b * 4 + wave;                  // [0,1024)
        const int row = (j >> 8) * II + D_MODEL + (j & 255);
        const float* wr = WihF + (size_t)row * (size_t)D_MODEL;
        float s = 0.f;
        #pragma unroll
        for (int p = 0; p < 7; ++p) {
            const int jj = p * 256 + lane * 4;
            float4 a = *(const float4*)(wr + jj);
            float4 v = *(const float4*)(x5 + jj);
            s += a.x * v.x + a.y * v.y + a.z * v.z + a.w * v.w;
        }
        s = waveReduce(s);
        if (lane == 0) gihF[j] = s + bihF[row] + bhhF[row];
    }
}

// ---------------------------------------------------------------------------
// K5: final cell, 256 blocks: row 1792+b -> out[b].
// ---------------------------------------------------------------------------
__global__ __launch_bounds__(256) void k5(
    const float* __restrict__ WhhF, const float* __restrict__ gihF,
    const float* __restrict__ h_in, const float* __restrict__ c,
    float* __restrict__ out)
{
    __shared__ float partial[4];
    const int tid = threadIdx.x, wave = tid >> 6, lane = tid & 63;
    const int b = blockIdx.x;                     // 0..255
    const int r = D_MODEL + b;

    const float* wr = WhhF + ((size_t)wave * II + r) * (size_t)II;
    float s = dotG(wr, h_in, lane);
    s = waveReduce(s);
    if (lane == 0) partial[wave] = s + gihF[wave * BB + b];
    __syncthreads();
    if (tid == 0) {
        const float cc = sigm(partial[1]) * c[r]
                       + sigm(partial[0]) * tanhf(partial[2]);
        out[b] = sigm(partial[3]) * tanhf(cc);
    }
}

extern "C" void kernel_launch(void* const* d_in, const int* in_sizes, int n_in,
                              void* d_out, int out_size, void* d_ws, size_t ws_size,
                              hipStream_t stream) {
    const float* x    = (const float*)d_in[0];
    const float* y    = (const float*)d_in[1];
    const float* Wih5 = (const float*)d_in[2];
    const float* Whh5 = (const float*)d_in[3];
    const float* bih5 = (const float*)d_in[4];
    const float* bhh5 = (const float*)d_in[5];
    const float* WihF = (const float*)d_in[6];
    const float* WhhF = (const float*)d_in[7];
    const float* bihF = (const float*)d_in[8];
    const float* bhhF = (const float*)d_in[9];
    float* out = (float*)d_out;

    float* ws   = (float*)d_ws;
    float* gihA = ws;                  // 8192
    float* gihB = gihA + FOURI;        // 8192
    float* gihF = gihB + FOURI;        // 1024
    float* hA   = gihF + 1024;         // 2048
    float* hB   = hA + II;             // 2048
    float* cbuf = hB + II;             // 2048

    const size_t WOFF = (size_t)FOURI * II;

    // K0: cell0 (f-gate skipped) + ih1 -> gihA ; h0 -> hA
    k_first<<<G, 256, 0, stream>>>(x, y, Wih5, bih5, bhh5, hA, cbuf, gihA);

    // K1: cell1 (gihA, hA->hB) + ih2 -> gihB
    k_mid<<<G, 256, 0, stream>>>(
        Whh5 + 1 * WOFF, gihA, hA, hB, cbuf,
        Wih5 + 2 * WOFF, bih5 + 2 * FOURI, bhh5 + 2 * FOURI,
        x + 2 * D_MODEL, y + 2 * BB, gihB);

    // K2: cell2 (gihB, hB->hA) + ih3 -> gihA
    k_mid<<<G, 256, 0, stream>>>(
        Whh5 + 2 * WOFF, gihB, hB, hA, cbuf,
        Wih5 + 3 * WOFF, bih5 + 3 * FOURI, bhh5 + 3 * FOURI,
        x + 3 * D_MODEL, y + 3 * BB, gihA);

    // K3: cell3 (gihA, hA->hB) + ih4 -> gihB
    k_mid<<<G, 256, 0, stream>>>(
        Whh5 + 3 * WOFF, gihA, hA, hB, cbuf,
        Wih5 + 4 * WOFF, bih5 + 4 * FOURI, bhh5 + 4 * FOURI,
        x + 4 * D_MODEL, y + 4 * BB, gihB);

    // K4: cell4 (gihB, hB->hA) + final-cell ih -> gihF
    k4<<<G, 256, 0, stream>>>(
        Whh5 + 4 * WOFF, gihB, hB, hA, cbuf,
        WihF, bihF, bhhF, x + 5 * D_MODEL, gihF);

    // K5: final cell -> out
    k5<<<BB, 256, 0, stream>>>(WhhF, gihF, hA, cbuf, out);
}